// Round 3
// baseline (68.835 us; speedup 1.0000x reference)
//
#include <hip/hip_runtime.h>

#define NQ 16
#define NL 4
#define NA 6
#define BATCH 512

// d_ws layout in float4 units:
//   [0 .. 95]        wmats: [3 layers][16 wires][2 rows]  (layers 2..4, compact)
//   [1024 ..]        a1   : [512][16][2 rows]             (merged RY(x)+Rot1, per sample)
// Row storage convention (enables address-select instead of cndmask):
//   row0 = (M00r, M00i, M01r, M01i)   -> for amps with window-bit = 0: n = M00*a + M01*p
//   row1 = (M11r, M11i, M10r, M10i)   -> for amps with window-bit = 1: n = M11*a + M10*p
#define A1_OFF 1024

__global__ __launch_bounds__(256)
void prep_kernel(const float* __restrict__ x,    // [512,16]
                 const float* __restrict__ wt,   // [4,16,3]
                 const float* __restrict__ fb,   // [6]
                 float4* __restrict__ ws,
                 float* __restrict__ out)        // [512,6] <- init to bias
{
    const int tid = threadIdx.x, blk = blockIdx.x;
    if (blk < 32) {
        // A1[b][w] = RY(th1) RZ(phi1) RY(x[b,w])
        const int t = blk * 256 + tid;          // 0..8191
        const int b = t >> 4, w = t & 15;
        const float phi = wt[w * 3 + 0], th = wt[w * 3 + 1];
        float sp, cp, st, ct, sx, cx;
        sincosf(0.5f * phi, &sp, &cp);
        sincosf(0.5f * th,  &st, &ct);
        sincosf(0.5f * x[b * NQ + w], &sx, &cx);
        // W = RY(th) RZ(phi)
        const float w00r =  ct * cp, w00i = -ct * sp;
        const float w01r = -st * cp, w01i = -st * sp;
        const float w10r =  st * cp, w10i = -st * sp;
        const float w11r =  ct * cp, w11i =  ct * sp;
        // A = W * RY(x),  RY(x) = [[cx,-sx],[sx,cx]] (real)
        const float a00r =  w00r * cx + w01r * sx, a00i =  w00i * cx + w01i * sx;
        const float a01r = -w00r * sx + w01r * cx, a01i = -w00i * sx + w01i * cx;
        const float a10r =  w10r * cx + w11r * sx, a10i =  w10i * cx + w11i * sx;
        const float a11r = -w10r * sx + w11r * cx, a11i = -w10i * sx + w11i * cx;
        ws[A1_OFF + t * 2 + 0] = make_float4(a00r, a00i, a01r, a01i);
        ws[A1_OFF + t * 2 + 1] = make_float4(a11r, a11i, a10r, a10i);
    } else if (blk == 32) {
        // Weight gates, layers l=2..4: A_l = RY(th_l) RZ(om_{l-1} + phi_l)
        if (tid < 48) {
            const int g = tid >> 4, w = tid & 15;      // g=0..2 -> layer l=g+1
            const int l = g + 1;
            const float al = wt[((l - 1) * NQ + w) * 3 + 2] + wt[(l * NQ + w) * 3 + 0];
            const float th = wt[(l * NQ + w) * 3 + 1];
            float sa, ca, st, ct;
            sincosf(0.5f * al, &sa, &ca);
            sincosf(0.5f * th, &st, &ct);
            // M00 = ct*ca - i ct*sa; M01 = -st*ca - i st*sa; M10 = st*ca - i st*sa; M11 = ct*ca + i ct*sa
            ws[tid * 2 + 0] = make_float4(ct * ca, -ct * sa, -st * ca, -st * sa);
            ws[tid * 2 + 1] = make_float4(ct * ca,  ct * sa,  st * ca, -st * sa);
        }
    } else {
        // out <- bias (atomicAdd target for the main kernel's FC partials)
        const int t = (blk - 33) * 256 + tid;
        if (t < BATCH * NA) out[t] = fb[t - (t / NA) * NA];
    }
}

// One wave = one (sample b, measured qubit qi). Window wires w = qi-3+j, j=0..6
// UNCLAMPED: out-of-range wires are fictitious |0> wires with identity gates
// (exact — zero-amplitude components carry the skipped/extra phases).
// jm == 3 always => all shuffle masks / row shifts / signs are compile-time.
// State: lane holds amps n0=2*lane (ar0,ai0), n1=2*lane+1 (ar1,ai1).
// Window bit 0 in-lane; bit j>0 = lane bit j-1.

__global__ __launch_bounds__(256, 8)
void qmain_kernel(const float4* __restrict__ ws,
                  const float* __restrict__ fw,   // [6,16]
                  float* __restrict__ out)        // [512,6] (+= partials)
{
    __shared__ float4 lm[4][NQ][2];   // [gate-layer][wire][row]
    __shared__ float zsh[4];

    const int tid = threadIdx.x;
    const int b   = blockIdx.x >> 2;

    if (tid < 128) {
        const int g = tid >> 5;
        ((float4*)lm)[tid] = (g == 0) ? ws[A1_OFF + (b << 5) + tid]
                                      : ws[tid - 32];
    }
    __syncthreads();

    const int lane = tid & 63;
    const int wv   = tid >> 6;
    const int qi   = ((blockIdx.x & 3) << 2) | wv;

    float ar0 = (lane == 0) ? 1.0f : 0.0f, ai0 = 0.0f;
    float ar1 = 0.0f, ai1 = 0.0f;

    const int n0 = lane << 1, n1 = n0 | 1;
    const float czs0 = (__popc((n0 & (n0 >> 1)) & 0x3F) & 1) ? -1.0f : 1.0f;
    const float czs1 = (__popc((n1 & (n1 >> 1)) & 0x3F) & 1) ? -1.0f : 1.0f;

#define GATE(J, G) do {                                                        \
    const int w_ = qi + (J) - 3;                                               \
    if (0 <= w_ && w_ < NQ) {                                                  \
        if ((J) == 0) {                                                        \
            const float4 r0 = lm[G][w_][0], r1 = lm[G][w_][1];                 \
            const float nr0 = r0.x*ar0 - r0.y*ai0 + r0.z*ar1 - r0.w*ai1;       \
            const float ni0 = r0.x*ai0 + r0.y*ar0 + r0.z*ai1 + r0.w*ar1;       \
            const float nr1 = r1.z*ar0 - r1.w*ai0 + r1.x*ar1 - r1.y*ai1;       \
            const float ni1 = r1.z*ai0 + r1.w*ar0 + r1.x*ai1 + r1.y*ar1;       \
            ar0 = nr0; ai0 = ni0; ar1 = nr1; ai1 = ni1;                        \
        } else {                                                               \
            const int m_   = 1 << ((J) - 1);                                   \
            const int row_ = (lane >> ((J) - 1)) & 1;                          \
            const float4 c = lm[G][w_][row_];                                  \
            const float pr0 = __shfl_xor(ar0, m_, 64);                         \
            const float pi0 = __shfl_xor(ai0, m_, 64);                         \
            const float pr1 = __shfl_xor(ar1, m_, 64);                         \
            const float pi1 = __shfl_xor(ai1, m_, 64);                         \
            const float t0r = c.x*ar0 - c.y*ai0 + c.z*pr0 - c.w*pi0;           \
            const float t0i = c.x*ai0 + c.y*ar0 + c.z*pi0 + c.w*pr0;           \
            const float t1r = c.x*ar1 - c.y*ai1 + c.z*pr1 - c.w*pi1;           \
            const float t1i = c.x*ai1 + c.y*ar1 + c.z*pi1 + c.w*pr1;           \
            ar0 = t0r; ai0 = t0i; ar1 = t1r; ai1 = t1i;                        \
        }                                                                      \
    }                                                                          \
} while (0)

#define CZ() do { ar0 *= czs0; ai0 *= czs0; ar1 *= czs1; ai1 *= czs1; } while (0)

    // light cone: layer g touches window slots j in [g, 6-g]
    GATE(0,0); GATE(1,0); GATE(2,0); GATE(3,0); GATE(4,0); GATE(5,0); GATE(6,0);
    CZ();
    GATE(1,1); GATE(2,1); GATE(3,1); GATE(4,1); GATE(5,1);
    CZ();
    GATE(2,2); GATE(3,2); GATE(4,2);
    CZ();
    GATE(3,3);

#undef GATE
#undef CZ

    // <Z_qi>: measured bit = window bit 3 = lane bit 2 (same for n0, n1)
    const float sm = ((lane >> 2) & 1) ? -1.0f : 1.0f;
    float p = sm * (ar0*ar0 + ai0*ai0 + ar1*ar1 + ai1*ai1);
#pragma unroll
    for (int off = 32; off > 0; off >>= 1)
        p += __shfl_xor(p, off, 64);

    if (lane == 0) zsh[wv] = p;
    __syncthreads();

    // FC partial: this block owns 4 consecutive qi for sample b
    if (tid < NA) {
        const int q0 = (blockIdx.x & 3) << 2;
        const float* fwr = fw + tid * NQ + q0;
        const float acc = zsh[0]*fwr[0] + zsh[1]*fwr[1] + zsh[2]*fwr[2] + zsh[3]*fwr[3];
        atomicAdd(&out[b * NA + tid], acc);
    }
}

extern "C" void kernel_launch(void* const* d_in, const int* in_sizes, int n_in,
                              void* d_out, int out_size, void* d_ws, size_t ws_size,
                              hipStream_t stream) {
    const float* x    = (const float*)d_in[0];   // [512,16]
    const float* wts  = (const float*)d_in[1];   // [4,16,3]
    const float* fc_w = (const float*)d_in[2];   // [6,16]
    const float* fc_b = (const float*)d_in[3];   // [6]
    float* out  = (float*)d_out;                 // [512,6]
    float4* ws4 = (float4*)d_ws;

    // blocks 0..31: A1 mats; block 32: weight mats; blocks 33..44: out<-bias
    prep_kernel<<<45, 256, 0, stream>>>(x, wts, fc_b, ws4, out);
    // 2048 blocks x 4 waves: wave = (b, qi)
    qmain_kernel<<<2048, 256, 0, stream>>>(ws4, fc_w, out);
}

// Round 5
// 66.496 us; speedup vs baseline: 1.0352x; 1.0352x over previous
//
#include <hip/hip_runtime.h>

#define NQ 16
#define NL 4
#define NA 6
#define BATCH 512

// One block = one sample; 16 waves, wave qi computes <Z_qi> on an exact
// 7-qubit light-cone window centered at qi (wires qi-3 .. qi+3, UNCLAMPED:
// out-of-range wires are fictitious |0> wires with identity gates — exact,
// since components with a 1 on a fictitious wire have zero amplitude).
// Measured bit is always window bit 3 => compile-time masks everywhere.
//
// Transformed circuit (exact): per wire, A1 = RY(th1) RZ(phi1) RY(x);
// A_l = RY(th_l) RZ(om_{l-1}+phi_l) for l=2..4; CZ chains between layers;
// trailing RZ(om4) and final CZ are diagonal -> dropped. Light cone:
// layer g touches window slots [g, 6-g] -> 7+5+3+1 = 16 gates per wave.
//
// State: lane holds amps n0=2*lane (ar0,ai0), n1=2*lane+1 (ar1,ai1).
// Window bit 0 in-lane; bit j>0 = lane bit j-1 (shfl_xor partner).
// LDS row convention (address-select instead of cndmask):
//   row0 = (M00r,M00i,M01r,M01i) ; row1 = (M11r,M11i,M10r,M10i)

__global__ __launch_bounds__(1024, 8)
void qdqn_one_kernel(const float* __restrict__ x,    // [512,16]
                     const float* __restrict__ wt,   // [4,16,3]
                     const float* __restrict__ fw,   // [6,16]
                     const float* __restrict__ fb,   // [6]
                     float* __restrict__ out)        // [512,6]
{
    __shared__ float4 lm[4][NQ][2];   // [gate-layer][wire][row]
    __shared__ float zsh[NQ];

    const int tid = threadIdx.x;
    const int b   = blockIdx.x;

    // ---- Phase A: 64 threads build all gate matrices into LDS ----
    if (tid < 64) {
        const int w = tid & 15;
        const int g = tid >> 4;                 // 0 -> A1, 1..3 -> layers 2..4
        float4 R0, R1;
        if (g == 0) {
            const float phi = wt[w * 3 + 0], th = wt[w * 3 + 1];
            float sp, cp, st, ct, sx, cx;
            sincosf(0.5f * phi, &sp, &cp);
            sincosf(0.5f * th,  &st, &ct);
            sincosf(0.5f * x[b * NQ + w], &sx, &cx);
            // W = RY(th) RZ(phi)
            const float w00r =  ct * cp, w00i = -ct * sp;
            const float w01r = -st * cp, w01i = -st * sp;
            const float w10r =  st * cp, w10i = -st * sp;
            const float w11r =  ct * cp, w11i =  ct * sp;
            // A1 = W * RY(x)
            R0 = make_float4( w00r*cx + w01r*sx,  w00i*cx + w01i*sx,
                             -w00r*sx + w01r*cx, -w00i*sx + w01i*cx);
            R1 = make_float4(-w10r*sx + w11r*cx, -w10i*sx + w11i*cx,   // M11
                              w10r*cx + w11r*sx,  w10i*cx + w11i*sx);  // M10
        } else {
            const float al = wt[((g - 1) * NQ + w) * 3 + 2] + wt[(g * NQ + w) * 3 + 0];
            const float th = wt[(g * NQ + w) * 3 + 1];
            float sa, ca, st, ct;
            sincosf(0.5f * al, &sa, &ca);
            sincosf(0.5f * th, &st, &ct);
            R0 = make_float4(ct * ca, -ct * sa, -st * ca, -st * sa);   // M00,M01
            R1 = make_float4(ct * ca,  ct * sa,  st * ca, -st * sa);   // M11,M10
        }
        lm[g][w][0] = R0;
        lm[g][w][1] = R1;
    }
    __syncthreads();

    // ---- Phase B: wave qi simulates its window ----
    const int lane = tid & 63;
    const int qi   = tid >> 6;                  // 0..15

    float ar0 = (lane == 0) ? 1.0f : 0.0f, ai0 = 0.0f;
    float ar1 = 0.0f, ai1 = 0.0f;

    const int n0 = lane << 1, n1 = n0 | 1;
    const float czs0 = (__popc((n0 & (n0 >> 1)) & 0x3F) & 1) ? -1.0f : 1.0f;
    const float czs1 = (__popc((n1 & (n1 >> 1)) & 0x3F) & 1) ? -1.0f : 1.0f;

#define GATE(J, G) do {                                                        \
    const int w_ = qi + (J) - 3;                                               \
    if (0 <= w_ && w_ < NQ) {  /* wave-uniform */                              \
        if ((J) == 0) {                                                        \
            const float4 r0 = lm[G][w_][0], r1 = lm[G][w_][1];                 \
            const float nr0 = r0.x*ar0 - r0.y*ai0 + r0.z*ar1 - r0.w*ai1;       \
            const float ni0 = r0.x*ai0 + r0.y*ar0 + r0.z*ai1 + r0.w*ar1;       \
            const float nr1 = r1.z*ar0 - r1.w*ai0 + r1.x*ar1 - r1.y*ai1;       \
            const float ni1 = r1.z*ai0 + r1.w*ar0 + r1.x*ai1 + r1.y*ar1;       \
            ar0 = nr0; ai0 = ni0; ar1 = nr1; ai1 = ni1;                        \
        } else {                                                               \
            const int m_   = 1 << ((J) - 1);                                   \
            const int row_ = (lane >> ((J) - 1)) & 1;                          \
            const float4 c = lm[G][w_][row_];                                  \
            const float pr0 = __shfl_xor(ar0, m_, 64);                         \
            const float pi0 = __shfl_xor(ai0, m_, 64);                         \
            const float pr1 = __shfl_xor(ar1, m_, 64);                         \
            const float pi1 = __shfl_xor(ai1, m_, 64);                         \
            const float t0r = c.x*ar0 - c.y*ai0 + c.z*pr0 - c.w*pi0;           \
            const float t0i = c.x*ai0 + c.y*ar0 + c.z*pi0 + c.w*pr0;           \
            const float t1r = c.x*ar1 - c.y*ai1 + c.z*pr1 - c.w*pi1;           \
            const float t1i = c.x*ai1 + c.y*ar1 + c.z*pi1 + c.w*pr1;           \
            ar0 = t0r; ai0 = t0i; ar1 = t1r; ai1 = t1i;                        \
        }                                                                      \
    }                                                                          \
} while (0)

#define CZ() do { ar0 *= czs0; ai0 *= czs0; ar1 *= czs1; ai1 *= czs1; } while (0)

    GATE(0,0); GATE(1,0); GATE(2,0); GATE(3,0); GATE(4,0); GATE(5,0); GATE(6,0);
    CZ();
    GATE(1,1); GATE(2,1); GATE(3,1); GATE(4,1); GATE(5,1);
    CZ();
    GATE(2,2); GATE(3,2); GATE(4,2);
    CZ();
    GATE(3,3);

#undef GATE
#undef CZ

    // <Z_qi>: measured bit = window bit 3 = lane bit 2
    const float sm = ((lane >> 2) & 1) ? -1.0f : 1.0f;
    float p = sm * (ar0*ar0 + ai0*ai0 + ar1*ar1 + ai1*ai1);
#pragma unroll
    for (int off = 32; off > 0; off >>= 1)
        p += __shfl_xor(p, off, 64);
    if (lane == 0) zsh[qi] = p;
    __syncthreads();

    // ---- Phase C: FC epilogue ----
    if (tid < NA) {
        float acc = fb[tid];
#pragma unroll
        for (int i = 0; i < NQ; ++i)
            acc += zsh[i] * fw[tid * NQ + i];
        out[b * NA + tid] = acc;
    }
}

extern "C" void kernel_launch(void* const* d_in, const int* in_sizes, int n_in,
                              void* d_out, int out_size, void* d_ws, size_t ws_size,
                              hipStream_t stream) {
    const float* x    = (const float*)d_in[0];   // [512,16]
    const float* wts  = (const float*)d_in[1];   // [4,16,3]
    const float* fc_w = (const float*)d_in[2];   // [6,16]
    const float* fc_b = (const float*)d_in[3];   // [6]
    float* out = (float*)d_out;                  // [512,6]

    qdqn_one_kernel<<<BATCH, 1024, 0, stream>>>(x, wts, fc_w, fc_b, out);
}

// Round 6
// 63.897 us; speedup vs baseline: 1.0773x; 1.0407x over previous
//
#include <hip/hip_runtime.h>

#define NQ 16
#define NA 6
#define BATCH 512

// One block = one sample; 16 waves, wave qi computes <Z_qi> on an exact
// 7-qubit light-cone window (wires qi-3..qi+3, UNCLAMPED: fictitious wires
// carry identity gates on |0> — exact, zero-amplitude support).
//
// Exact transformations used:
//  * After layer 1 the state is a PRODUCT state: vec[w] = A1_w|0>,
//    A1 = RY(th1) RZ(phi1) RY(x). Lanes build amps as 7-factor products.
//  * Layers 2..4: A_l = RY(th_l) RZ(om_{l-1}+phi_l) (RZ commuted through CZ);
//    trailing RZ(om4) dropped into the measurement fold.
//  * Final gate folded into measurement: M = A4' Z A4 =
//    [[c, -s e^{ia}], [-s e^{-ia}, -c]], c=cos th4, s=sin th4, a=om3+phi4.
//  * CZ chains: per-amp precomputed sign (adjacent-1-pair parity).
//
// State: lane holds amps n0=2*lane (ar0,ai0), n1=2*lane+1 (ar1,ai1).
// Window bit 0 in-lane; bit j>0 = lane bit j-1. Measured bit = 3 = lane bit 2.
// LDS guard entries (index w+3, identity for w outside [0,16)) -> branchless.
// Gate row convention: row0=(M00r,M00i,M01r,M01i); row1=(M11r,M11i,M10r,M10i).

__global__ __launch_bounds__(1024, 8)
void qdqn_kernel(const float* __restrict__ x,    // [512,16]
                 const float* __restrict__ wt,   // [4,16,3]
                 const float* __restrict__ fw,   // [6,16]
                 const float* __restrict__ fb,   // [6]
                 float* __restrict__ out)        // [512,6]
{
    __shared__ float4 vec[22];     // idx w+3: (alpha_r, alpha_i, beta_r, beta_i)
    __shared__ float4 g2[22][2];   // layer-2 gate rows (guarded)
    __shared__ float4 g3[22][2];   // layer-3 gate rows (guarded)
    __shared__ float4 meas[16];    // (c, -s*cos a, -s*sin a, 0)
    __shared__ float  zsh[NQ];

    const int tid  = threadIdx.x;
    const int b    = blockIdx.x;
    const int lane = tid & 63;
    const int wv   = tid >> 6;

    // ---- Phase A: 4 waves build LDS tables (others idle to barrier) ----
    if (wv == 0) {
        if (lane < 22) {
            const int w = lane - 3;
            float4 r = make_float4(1.0f, 0.0f, 0.0f, 0.0f);   // identity|0>
            if (0 <= w && w < NQ) {
                float sp, cp, st, ct, sx, cx;
                __sincosf(0.5f * wt[w * 3 + 0], &sp, &cp);
                __sincosf(0.5f * wt[w * 3 + 1], &st, &ct);
                __sincosf(0.5f * x[b * NQ + w], &sx, &cx);
                r = make_float4(cp * (ct * cx - st * sx), -sp * (ct * cx + st * sx),
                                cp * (st * cx + ct * sx),  sp * (ct * sx - st * cx));
            }
            vec[lane] = r;
        }
    } else if (wv == 1) {
        if (lane < 22) {
            const int w = lane - 3;
            float4 R0 = make_float4(1.0f, 0.0f, 0.0f, 0.0f);
            float4 R1 = make_float4(1.0f, 0.0f, 0.0f, 0.0f);
            if (0 <= w && w < NQ) {
                const float al = wt[(0 * NQ + w) * 3 + 2] + wt[(1 * NQ + w) * 3 + 0];
                const float th = wt[(1 * NQ + w) * 3 + 1];
                float sa, ca, st, ct;
                __sincosf(0.5f * al, &sa, &ca);
                __sincosf(0.5f * th, &st, &ct);
                R0 = make_float4(ct * ca, -ct * sa, -st * ca, -st * sa);
                R1 = make_float4(ct * ca,  ct * sa,  st * ca, -st * sa);
            }
            g2[lane][0] = R0; g2[lane][1] = R1;
        }
    } else if (wv == 2) {
        if (lane < 22) {
            const int w = lane - 3;
            float4 R0 = make_float4(1.0f, 0.0f, 0.0f, 0.0f);
            float4 R1 = make_float4(1.0f, 0.0f, 0.0f, 0.0f);
            if (0 <= w && w < NQ) {
                const float al = wt[(1 * NQ + w) * 3 + 2] + wt[(2 * NQ + w) * 3 + 0];
                const float th = wt[(2 * NQ + w) * 3 + 1];
                float sa, ca, st, ct;
                __sincosf(0.5f * al, &sa, &ca);
                __sincosf(0.5f * th, &st, &ct);
                R0 = make_float4(ct * ca, -ct * sa, -st * ca, -st * sa);
                R1 = make_float4(ct * ca,  ct * sa,  st * ca, -st * sa);
            }
            g3[lane][0] = R0; g3[lane][1] = R1;
        }
    } else if (wv == 3) {
        if (lane < NQ) {
            const int w = lane;
            const float th = wt[(3 * NQ + w) * 3 + 1];
            const float al = wt[(2 * NQ + w) * 3 + 2] + wt[(3 * NQ + w) * 3 + 0];
            float s4, c4, sa, ca;
            __sincosf(th, &s4, &c4);       // FULL angles here
            __sincosf(al, &sa, &ca);
            meas[w] = make_float4(c4, -s4 * ca, -s4 * sa, 0.0f);
        }
    }
    __syncthreads();

    // ---- Phase B: wave qi simulates its window ----
    const int qi = wv;

    // product-state init: P = prod_{j=1..6} vec[qi+j][lane bit j-1]
    float Pr, Pi;
    {
        const float2* vp = reinterpret_cast<const float2*>(vec);
        float2 f = vp[((qi + 1) << 1) + (lane & 1)];
        Pr = f.x; Pi = f.y;
#pragma unroll
        for (int j = 2; j <= 6; ++j) {
            const float2 g = vp[((qi + j) << 1) + ((lane >> (j - 1)) & 1)];
            const float nr = Pr * g.x - Pi * g.y;
            const float ni = Pr * g.y + Pi * g.x;
            Pr = nr; Pi = ni;
        }
    }
    const float4 v0 = vec[qi];   // slot 0 wire (guarded)
    float ar0 = Pr * v0.x - Pi * v0.y, ai0 = Pr * v0.y + Pi * v0.x;
    float ar1 = Pr * v0.z - Pi * v0.w, ai1 = Pr * v0.w + Pi * v0.z;

    const int n0 = lane << 1, n1 = n0 | 1;
    const float czs0 = (__popc((n0 & (n0 >> 1)) & 0x3F) & 1) ? -1.0f : 1.0f;
    const float czs1 = (__popc((n1 & (n1 >> 1)) & 0x3F) & 1) ? -1.0f : 1.0f;

#define CZ() do { ar0 *= czs0; ai0 *= czs0; ar1 *= czs1; ai1 *= czs1; } while (0)
#define GATE(J, ARR) do {                                                      \
    const int  m_   = 1 << ((J) - 1);                                          \
    const int  row_ = (lane >> ((J) - 1)) & 1;                                 \
    const float4 c  = ARR[qi + (J)][row_];                                     \
    const float pr0 = __shfl_xor(ar0, m_, 64);                                 \
    const float pi0 = __shfl_xor(ai0, m_, 64);                                 \
    const float pr1 = __shfl_xor(ar1, m_, 64);                                 \
    const float pi1 = __shfl_xor(ai1, m_, 64);                                 \
    const float t0r = c.x*ar0 - c.y*ai0 + c.z*pr0 - c.w*pi0;                   \
    const float t0i = c.x*ai0 + c.y*ar0 + c.z*pi0 + c.w*pr0;                   \
    const float t1r = c.x*ar1 - c.y*ai1 + c.z*pr1 - c.w*pi1;                   \
    const float t1i = c.x*ai1 + c.y*ar1 + c.z*pi1 + c.w*pr1;                   \
    ar0 = t0r; ai0 = t0i; ar1 = t1r; ai1 = t1i;                                \
} while (0)

    CZ();
    GATE(1, g2); GATE(2, g2); GATE(3, g2); GATE(4, g2); GATE(5, g2);
    CZ();
    GATE(2, g3); GATE(3, g3); GATE(4, g3);
    CZ();

#undef GATE
#undef CZ

    // ---- folded measurement: <M>, M = [[c, sC+i sS],[sC-i sS, -c]] ----
    const float4 m  = meas[qi];
    const float sgn3 = ((lane >> 2) & 1) ? -1.0f : 1.0f;
    const float pr0 = __shfl_xor(ar0, 4, 64);
    const float pi0 = __shfl_xor(ai0, 4, 64);
    const float pr1 = __shfl_xor(ar1, 4, 64);
    const float pi1 = __shfl_xor(ai1, 4, 64);
    const float u  = ar0 * pr0 + ai0 * pi0 + ar1 * pr1 + ai1 * pi1;
    const float v  = ar0 * pi0 - ai0 * pr0 + ar1 * pi1 - ai1 * pr1;
    float p = sgn3 * (m.x * (ar0*ar0 + ai0*ai0 + ar1*ar1 + ai1*ai1) - m.z * v)
            + m.y * u;

#pragma unroll
    for (int off = 32; off > 0; off >>= 1)
        p += __shfl_xor(p, off, 64);
    if (lane == 0) zsh[qi] = p;
    __syncthreads();

    // ---- FC epilogue ----
    if (tid < NA) {
        float acc = fb[tid];
#pragma unroll
        for (int i = 0; i < NQ; ++i)
            acc += zsh[i] * fw[tid * NQ + i];
        out[b * NA + tid] = acc;
    }
}

extern "C" void kernel_launch(void* const* d_in, const int* in_sizes, int n_in,
                              void* d_out, int out_size, void* d_ws, size_t ws_size,
                              hipStream_t stream) {
    const float* x    = (const float*)d_in[0];   // [512,16]
    const float* wts  = (const float*)d_in[1];   // [4,16,3]
    const float* fc_w = (const float*)d_in[2];   // [6,16]
    const float* fc_b = (const float*)d_in[3];   // [6]
    float* out = (float*)d_out;                  // [512,6]

    qdqn_kernel<<<BATCH, 1024, 0, stream>>>(x, wts, fc_w, fc_b, out);
}

// Round 7
// 63.048 us; speedup vs baseline: 1.0918x; 1.0135x over previous
//
#include <hip/hip_runtime.h>

#define NQ 16
#define NA 6
#define BATCH 512

// One block = one sample; 8 waves; wave wv runs TWO chains qi=wv and qi=wv+8.
// Each chain: <Z_qi> on an exact 7-qubit light-cone window (wires qi-3..qi+3,
// UNCLAMPED: fictitious wires = identity gates on |0>, exact on zero-amp support).
//
// Exact transformations:
//  * Layer 1 leaves a PRODUCT state: vec[w] = RY(th1)RZ(phi1)RY(x)|0>.
//  * A_l = RY(th_l) RZ(om_{l-1}+phi_l) for l=2,3 (RZ commuted through CZ).
//  * Layer-4 gate, CZ3, and the layer-3 gate on the measured wire are ALL
//    folded into the measurement operator:
//      H = G3(m)' [CZ3' (A4' Z A4) CZ3] G3(m) = H1 + H2 (x) Z(l)Z(r)
//    H1,H2 Hermitian traceless 2x2, built numerically in Phase A.
//    Z(l)Z(r) on neighbor wires -> per-lane sign (lane bits 1,3).
//  * CZ1, CZ2: per-amp precomputed sign (adjacent-1-pair parity).
//
// State: lane holds amps n0=2*lane (ar0,ai0), n1=2*lane+1 (ar1,ai1).
// Window bit 0 in-lane; bit j>0 = lane bit j-1. Measured bit = lane bit 2.
// Gate row convention: row0=(M00r,M00i,M01r,M01i); row1=(M11r,M11i,M10r,M10i).

__global__ __launch_bounds__(512, 4)
void qdqn_kernel(const float* __restrict__ x,    // [512,16]
                 const float* __restrict__ wt,   // [4,16,3]
                 const float* __restrict__ fw,   // [6,16]
                 const float* __restrict__ fb,   // [6]
                 float* __restrict__ out)        // [512,6]
{
    __shared__ float4 vec[22];        // idx w+3: (a_r, a_i, b_r, b_i) = A1|0>
    __shared__ float4 g2[22][2];      // layer-2 gate rows (guarded identity)
    __shared__ float4 g3[22][2];      // layer-3 gate rows (guarded identity)
    __shared__ float4 measA[16];      // (a1, b1r, b1i, a2)
    __shared__ float4 measB[16];      // (b2r, b2i, -, -)
    __shared__ float  zsh[NQ];

    const int tid  = threadIdx.x;
    const int b    = blockIdx.x;
    const int lane = tid & 63;
    const int wv   = tid >> 6;        // 0..7

    // ---- Phase A: waves 0-3 build LDS tables ----
    if (wv == 0) {
        if (lane < 22) {
            const int w = lane - 3;
            float4 r = make_float4(1.0f, 0.0f, 0.0f, 0.0f);
            if (0 <= w && w < NQ) {
                float sp, cp, st, ct, sx, cx;
                __sincosf(0.5f * wt[w * 3 + 0], &sp, &cp);
                __sincosf(0.5f * wt[w * 3 + 1], &st, &ct);
                __sincosf(0.5f * x[b * NQ + w], &sx, &cx);
                r = make_float4(cp * (ct * cx - st * sx), -sp * (ct * cx + st * sx),
                                cp * (st * cx + ct * sx),  sp * (ct * sx - st * cx));
            }
            vec[lane] = r;
        }
    } else if (wv == 1) {
        if (lane < 22) {
            const int w = lane - 3;
            float4 R0 = make_float4(1.0f, 0.0f, 0.0f, 0.0f);
            float4 R1 = make_float4(1.0f, 0.0f, 0.0f, 0.0f);
            if (0 <= w && w < NQ) {
                const float al = wt[(0 * NQ + w) * 3 + 2] + wt[(1 * NQ + w) * 3 + 0];
                const float th = wt[(1 * NQ + w) * 3 + 1];
                float sa, ca, st, ct;
                __sincosf(0.5f * al, &sa, &ca);
                __sincosf(0.5f * th, &st, &ct);
                R0 = make_float4(ct * ca, -ct * sa, -st * ca, -st * sa);
                R1 = make_float4(ct * ca,  ct * sa,  st * ca, -st * sa);
            }
            g2[lane][0] = R0; g2[lane][1] = R1;
        }
    } else if (wv == 2) {
        if (lane < 22) {
            const int w = lane - 3;
            float4 R0 = make_float4(1.0f, 0.0f, 0.0f, 0.0f);
            float4 R1 = make_float4(1.0f, 0.0f, 0.0f, 0.0f);
            if (0 <= w && w < NQ) {
                const float al = wt[(1 * NQ + w) * 3 + 2] + wt[(2 * NQ + w) * 3 + 0];
                const float th = wt[(2 * NQ + w) * 3 + 1];
                float sa, ca, st, ct;
                __sincosf(0.5f * al, &sa, &ca);
                __sincosf(0.5f * th, &st, &ct);
                R0 = make_float4(ct * ca, -ct * sa, -st * ca, -st * sa);
                R1 = make_float4(ct * ca,  ct * sa,  st * ca, -st * sa);
            }
            g3[lane][0] = R0; g3[lane][1] = R1;
        }
    } else if (wv == 3) {
        if (lane < NQ) {
            const int w = lane;
            // G = layer-3 gate on w (half angles); M from A4 fold (full angles)
            float st, ct, sb, cb, s4, c4, sa, ca;
            __sincosf(0.5f * wt[(2 * NQ + w) * 3 + 1], &st, &ct);
            __sincosf(0.5f * (wt[(1 * NQ + w) * 3 + 2] + wt[(2 * NQ + w) * 3 + 0]), &sb, &cb);
            __sincosf(wt[(3 * NQ + w) * 3 + 1], &s4, &c4);
            __sincosf(wt[(2 * NQ + w) * 3 + 2] + wt[(3 * NQ + w) * 3 + 0], &sa, &ca);
            // G entries
            const float G00r =  ct * cb, G00i = -ct * sb;
            const float G01r = -st * cb, G01i = -st * sb;
            const float G10r =  st * cb, G10i = -st * sb;
            const float G11r =  ct * cb, G11i =  ct * sb;
            const float M01r = -s4 * ca, M01i = -s4 * sa;
            // H1 = G' (c4 Z) G
            const float a1  = c4 * ((G00r*G00r + G00i*G00i) - (G10r*G10r + G10i*G10i));
            const float b1r = c4 * ((G00r*G01r + G00i*G01i) - (G10r*G11r + G10i*G11i));
            const float b1i = c4 * ((G00r*G01i - G00i*G01r) - (G10r*G11i - G10i*G11r));
            // H2 = G' (M01|0><1| + h.c.) G
            const float tr = G00r*G10r + G00i*G10i, ti = G00r*G10i - G00i*G10r; // conj(G00)G10
            const float a2 = 2.0f * (M01r * tr - M01i * ti);
            const float u1r = G00r*G11r + G00i*G11i, u1i = G00r*G11i - G00i*G11r; // conj(G00)G11
            const float u2r = G10r*G01r + G10i*G01i, u2i = G10r*G01i - G10i*G01r; // conj(G10)G01
            const float b2r = (M01r*u1r - M01i*u1i) + (M01r*u2r + M01i*u2i);
            const float b2i = (M01r*u1i + M01i*u1r) + (M01r*u2i - M01i*u2r);
            measA[w] = make_float4(a1, b1r, b1i, a2);
            measB[w] = make_float4(b2r, b2i, 0.0f, 0.0f);
        }
    }
    __syncthreads();

    // ---- Phase B: two chains per wave ----
    const int qiA = wv;
    const int qiB = wv + 8;

    const int n0 = lane << 1, n1 = n0 | 1;
    const float czs0 = (__popc((n0 & (n0 >> 1)) & 0x3F) & 1) ? -1.0f : 1.0f;
    const float czs1 = (__popc((n1 & (n1 >> 1)) & 0x3F) & 1) ? -1.0f : 1.0f;

    // product-state init, tree-structured
    const float2* vp = reinterpret_cast<const float2*>(vec);
    float Ar0, Ai0, Ar1, Ai1, Br0, Bi0, Br1, Bi1;
    {
        const int i1 = (lane & 1), i2 = ((lane >> 1) & 1), i3 = ((lane >> 2) & 1);
        const int i4 = ((lane >> 3) & 1), i5 = ((lane >> 4) & 1), i6 = ((lane >> 5) & 1);
#define PINIT(QI, r0, s0, r1, s1) do {                                          \
        const float2 f1 = vp[(((QI) + 1) << 1) + i1];                           \
        const float2 f2 = vp[(((QI) + 2) << 1) + i2];                           \
        const float2 f3 = vp[(((QI) + 3) << 1) + i3];                           \
        const float2 f4 = vp[(((QI) + 4) << 1) + i4];                           \
        const float2 f5 = vp[(((QI) + 5) << 1) + i5];                           \
        const float2 f6 = vp[(((QI) + 6) << 1) + i6];                           \
        const float t12r = f1.x*f2.x - f1.y*f2.y, t12i = f1.x*f2.y + f1.y*f2.x; \
        const float t34r = f3.x*f4.x - f3.y*f4.y, t34i = f3.x*f4.y + f3.y*f4.x; \
        const float t56r = f5.x*f6.x - f5.y*f6.y, t56i = f5.x*f6.y + f5.y*f6.x; \
        const float q_r = t12r*t34r - t12i*t34i, q_i = t12r*t34i + t12i*t34r;   \
        const float Pr = q_r*t56r - q_i*t56i,    Pi = q_r*t56i + q_i*t56r;      \
        const float4 v0 = vec[QI];                                              \
        r0 = Pr*v0.x - Pi*v0.y; s0 = Pr*v0.y + Pi*v0.x;                         \
        r1 = Pr*v0.z - Pi*v0.w; s1 = Pr*v0.w + Pi*v0.z;                         \
    } while (0)
        PINIT(qiA, Ar0, Ai0, Ar1, Ai1);
        PINIT(qiB, Br0, Bi0, Br1, Bi1);
#undef PINIT
    }

#define CZ2X() do {                                                            \
    Ar0 *= czs0; Ai0 *= czs0; Ar1 *= czs1; Ai1 *= czs1;                        \
    Br0 *= czs0; Bi0 *= czs0; Br1 *= czs1; Bi1 *= czs1;                        \
} while (0)

    // dual-chain gate on window slot J (shuffles issued back-to-back for ILP)
#define GATE2(J, ARR) do {                                                     \
    const int  m_   = 1 << ((J) - 1);                                          \
    const int  row_ = (lane >> ((J) - 1)) & 1;                                 \
    const float4 cA = ARR[qiA + (J)][row_];                                    \
    const float4 cB = ARR[qiB + (J)][row_];                                    \
    const float Apr0 = __shfl_xor(Ar0, m_, 64);                                \
    const float Api0 = __shfl_xor(Ai0, m_, 64);                                \
    const float Apr1 = __shfl_xor(Ar1, m_, 64);                                \
    const float Api1 = __shfl_xor(Ai1, m_, 64);                                \
    const float Bpr0 = __shfl_xor(Br0, m_, 64);                                \
    const float Bpi0 = __shfl_xor(Bi0, m_, 64);                                \
    const float Bpr1 = __shfl_xor(Br1, m_, 64);                                \
    const float Bpi1 = __shfl_xor(Bi1, m_, 64);                                \
    float t0r, t0i, t1r, t1i;                                                  \
    t0r = cA.x*Ar0 - cA.y*Ai0 + cA.z*Apr0 - cA.w*Api0;                         \
    t0i = cA.x*Ai0 + cA.y*Ar0 + cA.z*Api0 + cA.w*Apr0;                         \
    t1r = cA.x*Ar1 - cA.y*Ai1 + cA.z*Apr1 - cA.w*Api1;                         \
    t1i = cA.x*Ai1 + cA.y*Ar1 + cA.z*Api1 + cA.w*Apr1;                         \
    Ar0 = t0r; Ai0 = t0i; Ar1 = t1r; Ai1 = t1i;                                \
    t0r = cB.x*Br0 - cB.y*Bi0 + cB.z*Bpr0 - cB.w*Bpi0;                         \
    t0i = cB.x*Bi0 + cB.y*Br0 + cB.z*Bpi0 + cB.w*Bpr0;                         \
    t1r = cB.x*Br1 - cB.y*Bi1 + cB.z*Bpr1 - cB.w*Bpi1;                         \
    t1i = cB.x*Bi1 + cB.y*Br1 + cB.z*Bpi1 + cB.w*Bpr1;                         \
    Br0 = t0r; Bi0 = t0i; Br1 = t1r; Bi1 = t1i;                                \
} while (0)

    CZ2X();   // CZ1
    GATE2(1, g2); GATE2(2, g2); GATE2(3, g2); GATE2(4, g2); GATE2(5, g2);
    CZ2X();   // CZ2
    GATE2(2, g3); GATE2(4, g3);   // layer-3 off-center; center+CZ3 folded into meas

#undef GATE2
#undef CZ2X

    // ---- folded measurement: Heff = H1 + sgn_lr * H2 per lane ----
    const float sgn_lr = (((lane >> 1) ^ (lane >> 3)) & 1) ? -1.0f : 1.0f;
    const float sgnm   = ((lane >> 2) & 1) ? -1.0f : 1.0f;

    const float4 mA_A = measA[qiA], mB_A = measB[qiA];
    const float4 mA_B = measA[qiB], mB_B = measB[qiB];

    const float Apr0 = __shfl_xor(Ar0, 4, 64);
    const float Api0 = __shfl_xor(Ai0, 4, 64);
    const float Apr1 = __shfl_xor(Ar1, 4, 64);
    const float Api1 = __shfl_xor(Ai1, 4, 64);
    const float Bpr0 = __shfl_xor(Br0, 4, 64);
    const float Bpi0 = __shfl_xor(Bi0, 4, 64);
    const float Bpr1 = __shfl_xor(Br1, 4, 64);
    const float Bpi1 = __shfl_xor(Bi1, 4, 64);

    float pA, pB;
    {
        const float aE  = fmaf(sgn_lr, mA_A.w, mA_A.x);
        const float bEr = fmaf(sgn_lr, mB_A.x, mA_A.y);
        const float bEi = fmaf(sgn_lr, mB_A.y, mA_A.z);
        const float nn = Ar0*Ar0 + Ai0*Ai0 + Ar1*Ar1 + Ai1*Ai1;
        const float u  = Ar0*Apr0 + Ai0*Api0 + Ar1*Apr1 + Ai1*Api1;
        const float v  = Ar0*Api0 - Ai0*Apr0 + Ar1*Api1 - Ai1*Apr1;
        pA = sgnm * (aE * nn - bEi * v) + bEr * u;
    }
    {
        const float aE  = fmaf(sgn_lr, mA_B.w, mA_B.x);
        const float bEr = fmaf(sgn_lr, mB_B.x, mA_B.y);
        const float bEi = fmaf(sgn_lr, mB_B.y, mA_B.z);
        const float nn = Br0*Br0 + Bi0*Bi0 + Br1*Br1 + Bi1*Bi1;
        const float u  = Br0*Bpr0 + Bi0*Bpi0 + Br1*Bpr1 + Bi1*Bpi1;
        const float v  = Br0*Bpi0 - Bi0*Bpr0 + Br1*Bpi1 - Bi1*Bpr1;
        pB = sgnm * (aE * nn - bEi * v) + bEr * u;
    }

#pragma unroll
    for (int off = 32; off > 0; off >>= 1) {
        pA += __shfl_xor(pA, off, 64);
        pB += __shfl_xor(pB, off, 64);
    }
    if (lane == 0) { zsh[qiA] = pA; zsh[qiB] = pB; }
    __syncthreads();

    // ---- FC epilogue ----
    if (tid < NA) {
        float acc = fb[tid];
#pragma unroll
        for (int i = 0; i < NQ; ++i)
            acc += zsh[i] * fw[tid * NQ + i];
        out[b * NA + tid] = acc;
    }
}

extern "C" void kernel_launch(void* const* d_in, const int* in_sizes, int n_in,
                              void* d_out, int out_size, void* d_ws, size_t ws_size,
                              hipStream_t stream) {
    const float* x    = (const float*)d_in[0];   // [512,16]
    const float* wts  = (const float*)d_in[1];   // [4,16,3]
    const float* fc_w = (const float*)d_in[2];   // [6,16]
    const float* fc_b = (const float*)d_in[3];   // [6]
    float* out = (float*)d_out;                  // [512,6]

    qdqn_kernel<<<BATCH, 512, 0, stream>>>(x, wts, fc_w, fc_b, out);
}

// Round 8
// 61.800 us; speedup vs baseline: 1.1138x; 1.0202x over previous
//
#include <hip/hip_runtime.h>

#define NQ 16
#define NA 6
#define BATCH 512

// One block = 2 samples (512 threads, 8 waves). Wave wv: sample sid=wv>>2.
// Each wave holds FOUR chains (measured qubits qi = ((wv&3)<<2) | (lane>>4)):
// a chain's 128 amps live on 16 lanes x 8 regs.
//   amp index n (7 bits, window slots 0..6 = wires qi-3..qi+3, UNCLAMPED):
//   bits 0..2 = register index r; bits 3..6 = lane bits 0..3 (ln = lane&15).
// Gates: slot1,slot2 (g2) and slot2 (g3) are IN-LANE (r bits 1,2; no shfl);
// slots 3,4,5 use shfl_xor masks 1,2,4 within the 16-lane group; the folded
// measurement pairs via mask 1 (slot 3).
//
// Exact algebra (same as prior passing round):
//  * layer-1 leaves product state vec[w] = RY(th1)RZ(phi1)RY(x)|0>
//  * A_l = RY(th_l) RZ(om_{l-1}+phi_l), l=2,3 (RZ commuted through CZ)
//  * layer-4 gate + CZ3 + layer-3 gate on measured wire folded into
//    measurement: H = H1 + H2 (x) Z(slot2) Z(slot4)
//  * CZ1/CZ2 sign (adjacent-1-pair parity of n) decomposed:
//    pairs (3,4),(4,5),(5,6) -> ln parity; (0,1),(1,2) -> per-reg const
//    (r=3,6 negative); (2,3) -> (r bit2)&(ln bit0) cross term.
// Gate row convention: row0=(M00r,M00i,M01r,M01i); row1=(M11r,M11i,M10r,M10i).

__global__ __launch_bounds__(512)
void qdqn_kernel(const float* __restrict__ x,    // [512,16]
                 const float* __restrict__ wt,   // [4,16,3]
                 const float* __restrict__ fw,   // [6,16]
                 const float* __restrict__ fb,   // [6]
                 float* __restrict__ out)        // [512,6]
{
    __shared__ float4 vec2[2][22];
    __shared__ float4 g2[22][2];
    __shared__ float4 g3[22][2];
    __shared__ float4 measA[16];
    __shared__ float4 measB[16];
    __shared__ float  zsh[2][NQ];

    const int tid  = threadIdx.x;
    const int blk  = blockIdx.x;
    const int lane = tid & 63;
    const int wv   = tid >> 6;        // 0..7

    // ---- Phase A: waves 0,4 -> per-sample vec; 1 -> g2; 2 -> g3; 3 -> meas
    if ((wv & 3) == 0) {
        if (lane < 22) {
            const int w = lane - 3;
            const int b = 2 * blk + (wv >> 2);
            float4 r = make_float4(1.0f, 0.0f, 0.0f, 0.0f);
            if (0 <= w && w < NQ) {
                float sp, cp, st, ct, sx, cx;
                __sincosf(0.5f * wt[w * 3 + 0], &sp, &cp);
                __sincosf(0.5f * wt[w * 3 + 1], &st, &ct);
                __sincosf(0.5f * x[b * NQ + w], &sx, &cx);
                r = make_float4(cp * (ct * cx - st * sx), -sp * (ct * cx + st * sx),
                                cp * (st * cx + ct * sx),  sp * (ct * sx - st * cx));
            }
            vec2[wv >> 2][lane] = r;
        }
    } else if (wv == 1) {
        if (lane < 22) {
            const int w = lane - 3;
            float4 R0 = make_float4(1.0f, 0.0f, 0.0f, 0.0f);
            float4 R1 = make_float4(1.0f, 0.0f, 0.0f, 0.0f);
            if (0 <= w && w < NQ) {
                const float al = wt[(0 * NQ + w) * 3 + 2] + wt[(1 * NQ + w) * 3 + 0];
                const float th = wt[(1 * NQ + w) * 3 + 1];
                float sa, ca, st, ct;
                __sincosf(0.5f * al, &sa, &ca);
                __sincosf(0.5f * th, &st, &ct);
                R0 = make_float4(ct * ca, -ct * sa, -st * ca, -st * sa);
                R1 = make_float4(ct * ca,  ct * sa,  st * ca, -st * sa);
            }
            g2[lane][0] = R0; g2[lane][1] = R1;
        }
    } else if (wv == 2) {
        if (lane < 22) {
            const int w = lane - 3;
            float4 R0 = make_float4(1.0f, 0.0f, 0.0f, 0.0f);
            float4 R1 = make_float4(1.0f, 0.0f, 0.0f, 0.0f);
            if (0 <= w && w < NQ) {
                const float al = wt[(1 * NQ + w) * 3 + 2] + wt[(2 * NQ + w) * 3 + 0];
                const float th = wt[(2 * NQ + w) * 3 + 1];
                float sa, ca, st, ct;
                __sincosf(0.5f * al, &sa, &ca);
                __sincosf(0.5f * th, &st, &ct);
                R0 = make_float4(ct * ca, -ct * sa, -st * ca, -st * sa);
                R1 = make_float4(ct * ca,  ct * sa,  st * ca, -st * sa);
            }
            g3[lane][0] = R0; g3[lane][1] = R1;
        }
    } else if (wv == 3) {
        if (lane < NQ) {
            const int w = lane;
            float st, ct, sb, cb, s4, c4, sa, ca;
            __sincosf(0.5f * wt[(2 * NQ + w) * 3 + 1], &st, &ct);
            __sincosf(0.5f * (wt[(1 * NQ + w) * 3 + 2] + wt[(2 * NQ + w) * 3 + 0]), &sb, &cb);
            __sincosf(wt[(3 * NQ + w) * 3 + 1], &s4, &c4);
            __sincosf(wt[(2 * NQ + w) * 3 + 2] + wt[(3 * NQ + w) * 3 + 0], &sa, &ca);
            const float G00r =  ct * cb, G00i = -ct * sb;
            const float G01r = -st * cb, G01i = -st * sb;
            const float G10r =  st * cb, G10i = -st * sb;
            const float G11r =  ct * cb, G11i =  ct * sb;
            const float M01r = -s4 * ca, M01i = -s4 * sa;
            const float a1  = c4 * ((G00r*G00r + G00i*G00i) - (G10r*G10r + G10i*G10i));
            const float b1r = c4 * ((G00r*G01r + G00i*G01i) - (G10r*G11r + G10i*G11i));
            const float b1i = c4 * ((G00r*G01i - G00i*G01r) - (G10r*G11i - G10i*G11r));
            const float tr = G00r*G10r + G00i*G10i, ti = G00r*G10i - G00i*G10r;
            const float a2 = 2.0f * (M01r * tr - M01i * ti);
            const float u1r = G00r*G11r + G00i*G11i, u1i = G00r*G11i - G00i*G11r;
            const float u2r = G10r*G01r + G10i*G01i, u2i = G10r*G01i - G10i*G01r;
            const float b2r = (M01r*u1r - M01i*u1i) + (M01r*u2r + M01i*u2i);
            const float b2i = (M01r*u1i + M01i*u1r) + (M01r*u2i - M01i*u2r);
            measA[w] = make_float4(a1, b1r, b1i, a2);
            measB[w] = make_float4(b2r, b2i, 0.0f, 0.0f);
        }
    }
    __syncthreads();

    // ---- Phase B ----
    const int sid = wv >> 2;
    const int qi  = ((wv & 3) << 2) | ((lane >> 4) & 3);
    const int ln  = lane & 15;
    const float4* vecS = vec2[sid];

    float sr[8], si[8];

    // product-state init: bits 0,1,2 <- slots 0,1,2 (per-reg), 3..6 <- ln
    {
        const float2* vp = reinterpret_cast<const float2*>(vecS);
        const float2 f3 = vp[((qi + 3) << 1) + (ln & 1)];
        const float2 f4 = vp[((qi + 4) << 1) + ((ln >> 1) & 1)];
        const float2 f5 = vp[((qi + 5) << 1) + ((ln >> 2) & 1)];
        const float2 f6 = vp[((qi + 6) << 1) + ((ln >> 3) & 1)];
        const float t34r = f3.x*f4.x - f3.y*f4.y, t34i = f3.x*f4.y + f3.y*f4.x;
        const float t56r = f5.x*f6.x - f5.y*f6.y, t56i = f5.x*f6.y + f5.y*f6.x;
        const float Pcr  = t34r*t56r - t34i*t56i, Pci  = t34r*t56i + t34i*t56r;
        const float4 v0 = vecS[qi], v1 = vecS[qi + 1], v2 = vecS[qi + 2];
        const float e00r = v0.x*v1.x - v0.y*v1.y, e00i = v0.x*v1.y + v0.y*v1.x;
        const float e10r = v0.z*v1.x - v0.w*v1.y, e10i = v0.z*v1.y + v0.w*v1.x;
        const float e01r = v0.x*v1.z - v0.y*v1.w, e01i = v0.x*v1.w + v0.y*v1.z;
        const float e11r = v0.z*v1.z - v0.w*v1.w, e11i = v0.z*v1.w + v0.w*v1.z;
        const float g0r = Pcr*v2.x - Pci*v2.y, g0i = Pcr*v2.y + Pci*v2.x;
        const float g1r = Pcr*v2.z - Pci*v2.w, g1i = Pcr*v2.w + Pci*v2.z;
        sr[0] = e00r*g0r - e00i*g0i;  si[0] = e00r*g0i + e00i*g0r;
        sr[1] = e10r*g0r - e10i*g0i;  si[1] = e10r*g0i + e10i*g0r;
        sr[2] = e01r*g0r - e01i*g0i;  si[2] = e01r*g0i + e01i*g0r;
        sr[3] = e11r*g0r - e11i*g0i;  si[3] = e11r*g0i + e11i*g0r;
        sr[4] = e00r*g1r - e00i*g1i;  si[4] = e00r*g1i + e00i*g1r;
        sr[5] = e10r*g1r - e10i*g1i;  si[5] = e10r*g1i + e10i*g1r;
        sr[6] = e01r*g1r - e01i*g1i;  si[6] = e01r*g1i + e01i*g1r;
        sr[7] = e11r*g1r - e11i*g1i;  si[7] = e11r*g1i + e11i*g1r;
    }

    const float czl = (__popc((ln & (ln >> 1)) & 7) & 1) ? -1.0f : 1.0f;
    const float czx = (ln & 1) ? -1.0f : 1.0f;
    const float czA = czl;            // regs r<4
    const float czB = czl * czx;      // regs r>=4 (cross pair (2,3))

#define CZ() do {                                                              \
    sr[0] *=  czA; si[0] *=  czA;  sr[1] *=  czA; si[1] *=  czA;               \
    sr[2] *=  czA; si[2] *=  czA;  sr[3] *= -czA; si[3] *= -czA;               \
    sr[4] *=  czB; si[4] *=  czB;  sr[5] *=  czB; si[5] *=  czB;               \
    sr[6] *= -czB; si[6] *= -czB;  sr[7] *=  czB; si[7] *=  czB;               \
} while (0)

#define INLANE_GATE(ARR, SLOT, P) do {                                         \
    const float4 R0 = ARR[qi + (SLOT)][0];                                     \
    const float4 R1 = ARR[qi + (SLOT)][1];                                     \
    _Pragma("unroll")                                                          \
    for (int r = 0; r < 8; ++r) {                                              \
        if (((r >> (P)) & 1) == 0) {                                           \
            const int q = r | (1 << (P));                                      \
            const float nr0 = R0.x*sr[r] - R0.y*si[r] + R0.z*sr[q] - R0.w*si[q]; \
            const float ni0 = R0.x*si[r] + R0.y*sr[r] + R0.z*si[q] + R0.w*sr[q]; \
            const float nr1 = R1.z*sr[r] - R1.w*si[r] + R1.x*sr[q] - R1.y*si[q]; \
            const float ni1 = R1.z*si[r] + R1.w*sr[r] + R1.x*si[q] + R1.y*sr[q]; \
            sr[r] = nr0; si[r] = ni0; sr[q] = nr1; si[q] = ni1;                \
        }                                                                      \
    }                                                                          \
} while (0)

#define SHFL_GATE(ARR, SLOT, T) do {                                           \
    const float4 c = ARR[qi + (SLOT)][(ln >> (T)) & 1];                        \
    float pr[8], pi[8];                                                        \
    _Pragma("unroll")                                                          \
    for (int r = 0; r < 8; ++r) {                                              \
        pr[r] = __shfl_xor(sr[r], 1 << (T), 64);                               \
        pi[r] = __shfl_xor(si[r], 1 << (T), 64);                               \
    }                                                                          \
    _Pragma("unroll")                                                          \
    for (int r = 0; r < 8; ++r) {                                              \
        const float nr = c.x*sr[r] - c.y*si[r] + c.z*pr[r] - c.w*pi[r];        \
        const float ni = c.x*si[r] + c.y*sr[r] + c.z*pi[r] + c.w*pr[r];        \
        sr[r] = nr; si[r] = ni;                                                \
    }                                                                          \
} while (0)

    CZ();                       // CZ1
    INLANE_GATE(g2, 1, 1);      // g2 slot1 -> r bit 1
    INLANE_GATE(g2, 2, 2);      // g2 slot2 -> r bit 2
    SHFL_GATE(g2, 3, 0);        // g2 slot3 -> ln bit 0
    SHFL_GATE(g2, 4, 1);        // g2 slot4 -> ln bit 1
    SHFL_GATE(g2, 5, 2);        // g2 slot5 -> ln bit 2
    CZ();                       // CZ2
    INLANE_GATE(g3, 2, 2);      // g3 slot2 -> r bit 2
    SHFL_GATE(g3, 4, 1);        // g3 slot4 -> ln bit 1

#undef CZ
#undef INLANE_GATE
#undef SHFL_GATE

    // ---- folded measurement: H1 + sgn*H2, pair partner = slot3 = ln bit 0
    const float4 mA = measA[qi], mB = measB[qi];
    const float s0 = ((ln >> 1) & 1) ? -1.0f : 1.0f;          // Z(slot4)
    const float aE_lo  = mA.x + s0 * mA.w,  aE_hi  = mA.x - s0 * mA.w;
    const float bEr_lo = mA.y + s0 * mB.x,  bEr_hi = mA.y - s0 * mB.x;
    const float bEi_lo = mA.z + s0 * mB.y,  bEi_hi = mA.z - s0 * mB.y;
    const float sgnm = (ln & 1) ? -1.0f : 1.0f;               // Z(slot3)

    float p = 0.0f;
    {
        float pr[8], pi[8];
#pragma unroll
        for (int r = 0; r < 8; ++r) {
            pr[r] = __shfl_xor(sr[r], 1, 64);
            pi[r] = __shfl_xor(si[r], 1, 64);
        }
#pragma unroll
        for (int r = 0; r < 8; ++r) {
            const float aE  = (r < 4) ? aE_lo  : aE_hi;       // Z(slot2)=r bit2
            const float bEr = (r < 4) ? bEr_lo : bEr_hi;
            const float bEi = (r < 4) ? bEi_lo : bEi_hi;
            const float nn = sr[r]*sr[r] + si[r]*si[r];
            const float u  = sr[r]*pr[r] + si[r]*pi[r];
            const float v  = sr[r]*pi[r] - si[r]*pr[r];
            p += sgnm * (aE * nn - bEi * v) + bEr * u;
        }
    }

    p += __shfl_xor(p, 1, 64);
    p += __shfl_xor(p, 2, 64);
    p += __shfl_xor(p, 4, 64);
    p += __shfl_xor(p, 8, 64);
    if ((lane & 15) == 0) zsh[sid][qi] = p;
    __syncthreads();

    // ---- FC epilogue, both samples in parallel ----
    const int sid2 = tid >> 8;
    const int t6   = tid & 255;
    if (t6 < NA) {
        float acc = fb[t6];
#pragma unroll
        for (int i = 0; i < NQ; ++i)
            acc += zsh[sid2][i] * fw[t6 * NQ + i];
        out[(2 * blk + sid2) * NA + t6] = acc;
    }
}

extern "C" void kernel_launch(void* const* d_in, const int* in_sizes, int n_in,
                              void* d_out, int out_size, void* d_ws, size_t ws_size,
                              hipStream_t stream) {
    const float* x    = (const float*)d_in[0];   // [512,16]
    const float* wts  = (const float*)d_in[1];   // [4,16,3]
    const float* fc_w = (const float*)d_in[2];   // [6,16]
    const float* fc_b = (const float*)d_in[3];   // [6]
    float* out = (float*)d_out;                  // [512,6]

    qdqn_kernel<<<BATCH / 2, 512, 0, stream>>>(x, wts, fc_w, fc_b, out);
}

// Round 9
// 61.294 us; speedup vs baseline: 1.1230x; 1.0082x over previous
//
#include <hip/hip_runtime.h>

#define NQ 16
#define NA 6
#define BATCH 512

// One block = 2 samples (512 threads, 8 waves). Wave wv: sample sid=wv>>2.
// Each wave holds FOUR chains (measured qubits qi = ((wv&3)<<2) | (lane>>4)):
// a chain's 128 amps live on 16 lanes x 8 regs.
//
// amp index n (7 bits, window slots 0..6 = wires qi-3..qi+3, UNCLAMPED):
//   slot2 -> r bit0, slot3 -> r bit1, slot4 -> r bit2   (CENTER slots in-reg)
//   slot0 -> ln bit0, slot1 -> ln bit1, slot5 -> ln bit2, slot6 -> ln bit3
// So: g2 slots 2,3,4 and g3 slots 2,4 are IN-LANE; only g2 slots 1,5 shuffle
// (masks 2,4); the folded measurement pairs on r bit1 -> fully in-lane.
//
// Exact algebra (identical to prior passing rounds):
//  * layer-1 leaves product state vec[w] = RY(th1)RZ(phi1)RY(x)|0>
//  * A_l = RY(th_l) RZ(om_{l-1}+phi_l), l=2,3 (RZ commuted through CZ)
//  * layer-4 gate + CZ3 + layer-3 gate on measured wire folded into
//    measurement: H = H1(slot3) + H2(slot3) (x) Z(slot2) Z(slot4)
//  * CZ1/CZ2 sign (adjacent-1-pair parity of n) decomposed:
//    (0,1),(5,6) -> ln parity; (2,3),(3,4) -> per-reg const (r=3,6 neg);
//    (1,2) -> ln1 & r0 cross; (4,5) -> r2 & ln2 cross.
// Gate row convention: row0=(M00r,M00i,M01r,M01i); row1=(M11r,M11i,M10r,M10i).

__global__ __launch_bounds__(512)
void qdqn_kernel(const float* __restrict__ x,    // [512,16]
                 const float* __restrict__ wt,   // [4,16,3]
                 const float* __restrict__ fw,   // [6,16]
                 const float* __restrict__ fb,   // [6]
                 float* __restrict__ out)        // [512,6]
{
    __shared__ float4 vec2[2][22];
    __shared__ float4 g2[22][2];
    __shared__ float4 g3[22][2];
    __shared__ float4 measA[16];
    __shared__ float4 measB[16];
    __shared__ float  zsh[2][NQ];

    const int tid  = threadIdx.x;
    const int blk  = blockIdx.x;
    const int lane = tid & 63;
    const int wv   = tid >> 6;        // 0..7

    // ---- Phase A: waves 0,4 -> per-sample vec; 1 -> g2; 2 -> g3; 3 -> meas
    if ((wv & 3) == 0) {
        if (lane < 22) {
            const int w = lane - 3;
            const int b = 2 * blk + (wv >> 2);
            float4 r = make_float4(1.0f, 0.0f, 0.0f, 0.0f);
            if (0 <= w && w < NQ) {
                float sp, cp, st, ct, sx, cx;
                __sincosf(0.5f * wt[w * 3 + 0], &sp, &cp);
                __sincosf(0.5f * wt[w * 3 + 1], &st, &ct);
                __sincosf(0.5f * x[b * NQ + w], &sx, &cx);
                r = make_float4(cp * (ct * cx - st * sx), -sp * (ct * cx + st * sx),
                                cp * (st * cx + ct * sx),  sp * (ct * sx - st * cx));
            }
            vec2[wv >> 2][lane] = r;
        }
    } else if (wv == 1) {
        if (lane < 22) {
            const int w = lane - 3;
            float4 R0 = make_float4(1.0f, 0.0f, 0.0f, 0.0f);
            float4 R1 = make_float4(1.0f, 0.0f, 0.0f, 0.0f);
            if (0 <= w && w < NQ) {
                const float al = wt[(0 * NQ + w) * 3 + 2] + wt[(1 * NQ + w) * 3 + 0];
                const float th = wt[(1 * NQ + w) * 3 + 1];
                float sa, ca, st, ct;
                __sincosf(0.5f * al, &sa, &ca);
                __sincosf(0.5f * th, &st, &ct);
                R0 = make_float4(ct * ca, -ct * sa, -st * ca, -st * sa);
                R1 = make_float4(ct * ca,  ct * sa,  st * ca, -st * sa);
            }
            g2[lane][0] = R0; g2[lane][1] = R1;
        }
    } else if (wv == 2) {
        if (lane < 22) {
            const int w = lane - 3;
            float4 R0 = make_float4(1.0f, 0.0f, 0.0f, 0.0f);
            float4 R1 = make_float4(1.0f, 0.0f, 0.0f, 0.0f);
            if (0 <= w && w < NQ) {
                const float al = wt[(1 * NQ + w) * 3 + 2] + wt[(2 * NQ + w) * 3 + 0];
                const float th = wt[(2 * NQ + w) * 3 + 1];
                float sa, ca, st, ct;
                __sincosf(0.5f * al, &sa, &ca);
                __sincosf(0.5f * th, &st, &ct);
                R0 = make_float4(ct * ca, -ct * sa, -st * ca, -st * sa);
                R1 = make_float4(ct * ca,  ct * sa,  st * ca, -st * sa);
            }
            g3[lane][0] = R0; g3[lane][1] = R1;
        }
    } else if (wv == 3) {
        if (lane < NQ) {
            const int w = lane;
            float st, ct, sb, cb, s4, c4, sa, ca;
            __sincosf(0.5f * wt[(2 * NQ + w) * 3 + 1], &st, &ct);
            __sincosf(0.5f * (wt[(1 * NQ + w) * 3 + 2] + wt[(2 * NQ + w) * 3 + 0]), &sb, &cb);
            __sincosf(wt[(3 * NQ + w) * 3 + 1], &s4, &c4);
            __sincosf(wt[(2 * NQ + w) * 3 + 2] + wt[(3 * NQ + w) * 3 + 0], &sa, &ca);
            const float G00r =  ct * cb, G00i = -ct * sb;
            const float G01r = -st * cb, G01i = -st * sb;
            const float G10r =  st * cb, G10i = -st * sb;
            const float G11r =  ct * cb, G11i =  ct * sb;
            const float M01r = -s4 * ca, M01i = -s4 * sa;
            const float a1  = c4 * ((G00r*G00r + G00i*G00i) - (G10r*G10r + G10i*G10i));
            const float b1r = c4 * ((G00r*G01r + G00i*G01i) - (G10r*G11r + G10i*G11i));
            const float b1i = c4 * ((G00r*G01i - G00i*G01r) - (G10r*G11i - G10i*G11r));
            const float tr = G00r*G10r + G00i*G10i, ti = G00r*G10i - G00i*G10r;
            const float a2 = 2.0f * (M01r * tr - M01i * ti);
            const float u1r = G00r*G11r + G00i*G11i, u1i = G00r*G11i - G00i*G11r;
            const float u2r = G10r*G01r + G10i*G01i, u2i = G10r*G01i - G10i*G01r;
            const float b2r = (M01r*u1r - M01i*u1i) + (M01r*u2r + M01i*u2i);
            const float b2i = (M01r*u1i + M01i*u1r) + (M01r*u2i - M01i*u2r);
            measA[w] = make_float4(a1, b1r, b1i, a2);
            measB[w] = make_float4(b2r, b2i, 0.0f, 0.0f);
        }
    }
    __syncthreads();

    // ---- Phase B ----
    const int sid = wv >> 2;
    const int qi  = ((wv & 3) << 2) | ((lane >> 4) & 3);
    const int ln  = lane & 15;
    const float4* vecS = vec2[sid];

    float sr[8], si[8];

    // product-state init: r bits 0,1,2 <- slots 2,3,4; ln bits <- slots 0,1,5,6
    {
        const float2* vp = reinterpret_cast<const float2*>(vecS);
        const float2 f0 = vp[((qi + 0) << 1) + (ln & 1)];
        const float2 f1 = vp[((qi + 1) << 1) + ((ln >> 1) & 1)];
        const float2 f5 = vp[((qi + 5) << 1) + ((ln >> 2) & 1)];
        const float2 f6 = vp[((qi + 6) << 1) + ((ln >> 3) & 1)];
        const float t01r = f0.x*f1.x - f0.y*f1.y, t01i = f0.x*f1.y + f0.y*f1.x;
        const float t56r = f5.x*f6.x - f5.y*f6.y, t56i = f5.x*f6.y + f5.y*f6.x;
        const float Pr   = t01r*t56r - t01i*t56i, Pi   = t01r*t56i + t01i*t56r;
        const float4 v2 = vecS[qi + 2], v3 = vecS[qi + 3], v4 = vecS[qi + 4];
        // A[r0][r1] = v2[r0] * v3[r1]
        const float a00r = v2.x*v3.x - v2.y*v3.y, a00i = v2.x*v3.y + v2.y*v3.x;
        const float a10r = v2.z*v3.x - v2.w*v3.y, a10i = v2.z*v3.y + v2.w*v3.x;
        const float a01r = v2.x*v3.z - v2.y*v3.w, a01i = v2.x*v3.w + v2.y*v3.z;
        const float a11r = v2.z*v3.z - v2.w*v3.w, a11i = v2.z*v3.w + v2.w*v3.z;
        // g[r2] = v4[r2] * P
        const float g0r = v4.x*Pr - v4.y*Pi, g0i = v4.x*Pi + v4.y*Pr;
        const float g1r = v4.z*Pr - v4.w*Pi, g1i = v4.z*Pi + v4.w*Pr;
        sr[0] = a00r*g0r - a00i*g0i;  si[0] = a00r*g0i + a00i*g0r;
        sr[1] = a10r*g0r - a10i*g0i;  si[1] = a10r*g0i + a10i*g0r;
        sr[2] = a01r*g0r - a01i*g0i;  si[2] = a01r*g0i + a01i*g0r;
        sr[3] = a11r*g0r - a11i*g0i;  si[3] = a11r*g0i + a11i*g0r;
        sr[4] = a00r*g1r - a00i*g1i;  si[4] = a00r*g1i + a00i*g1r;
        sr[5] = a10r*g1r - a10i*g1i;  si[5] = a10r*g1i + a10i*g1r;
        sr[6] = a01r*g1r - a01i*g1i;  si[6] = a01r*g1i + a01i*g1r;
        sr[7] = a11r*g1r - a11i*g1i;  si[7] = a11r*g1i + a11i*g1r;
    }

    // CZ signs: ln parity of pairs (0,1),(5,6); per-reg base (r=3,6 neg);
    // cross (1,2): ln1 & r0; cross (4,5): r2 & ln2.
    const float czl = (__popc((ln & (ln >> 1)) & 5) & 1) ? -1.0f : 1.0f;
    const float s1x = ((ln >> 1) & 1) ? -1.0f : 1.0f;   // for regs with r0=1
    const float s2x = ((ln >> 2) & 1) ? -1.0f : 1.0f;   // for regs with r2=1
    const float czA = czl;
    const float czB = czl * s1x;
    const float czC = czl * s2x;
    const float czD = czB * s2x;
    // m[] = [czA, czB, czA, -czB, czC, czD, -czC, czD]

#define CZ() do {                                                              \
    sr[0] *=  czA; si[0] *=  czA;  sr[1] *=  czB; si[1] *=  czB;               \
    sr[2] *=  czA; si[2] *=  czA;  sr[3] *= -czB; si[3] *= -czB;               \
    sr[4] *=  czC; si[4] *=  czC;  sr[5] *=  czD; si[5] *=  czD;               \
    sr[6] *= -czC; si[6] *= -czC;  sr[7] *=  czD; si[7] *=  czD;               \
} while (0)

#define INLANE_GATE(ARR, SLOT, P) do {                                         \
    const float4 R0 = ARR[qi + (SLOT)][0];                                     \
    const float4 R1 = ARR[qi + (SLOT)][1];                                     \
    _Pragma("unroll")                                                          \
    for (int r = 0; r < 8; ++r) {                                              \
        if (((r >> (P)) & 1) == 0) {                                           \
            const int q = r | (1 << (P));                                      \
            const float nr0 = R0.x*sr[r] - R0.y*si[r] + R0.z*sr[q] - R0.w*si[q]; \
            const float ni0 = R0.x*si[r] + R0.y*sr[r] + R0.z*si[q] + R0.w*sr[q]; \
            const float nr1 = R1.z*sr[r] - R1.w*si[r] + R1.x*sr[q] - R1.y*si[q]; \
            const float ni1 = R1.z*si[r] + R1.w*sr[r] + R1.x*si[q] + R1.y*sr[q]; \
            sr[r] = nr0; si[r] = ni0; sr[q] = nr1; si[q] = ni1;                \
        }                                                                      \
    }                                                                          \
} while (0)

#define SHFL_GATE(ARR, SLOT, T) do {                                           \
    const float4 c = ARR[qi + (SLOT)][(ln >> (T)) & 1];                        \
    float pr[8], pi[8];                                                        \
    _Pragma("unroll")                                                          \
    for (int r = 0; r < 8; ++r) {                                              \
        pr[r] = __shfl_xor(sr[r], 1 << (T), 64);                               \
        pi[r] = __shfl_xor(si[r], 1 << (T), 64);                               \
    }                                                                          \
    _Pragma("unroll")                                                          \
    for (int r = 0; r < 8; ++r) {                                              \
        const float nr = c.x*sr[r] - c.y*si[r] + c.z*pr[r] - c.w*pi[r];        \
        const float ni = c.x*si[r] + c.y*sr[r] + c.z*pi[r] + c.w*pr[r];        \
        sr[r] = nr; si[r] = ni;                                                \
    }                                                                          \
} while (0)

    CZ();                       // CZ1
    SHFL_GATE(g2, 1, 1);        // g2 slot1 -> ln bit 1
    INLANE_GATE(g2, 2, 0);      // g2 slot2 -> r bit 0
    INLANE_GATE(g2, 3, 1);      // g2 slot3 -> r bit 1
    INLANE_GATE(g2, 4, 2);      // g2 slot4 -> r bit 2
    SHFL_GATE(g2, 5, 2);        // g2 slot5 -> ln bit 2
    CZ();                       // CZ2
    INLANE_GATE(g3, 2, 0);      // g3 slot2 -> r bit 0
    INLANE_GATE(g3, 4, 2);      // g3 slot4 -> r bit 2

#undef CZ
#undef INLANE_GATE
#undef SHFL_GATE

    // ---- folded measurement, fully in-lane: pairs on r bit1 ----
    // H = [[aE,bE],[bE*,-aE]] per pair, aE = a1 + szz*a2, bE = b1 + szz*b2,
    // szz = (-1)^(r0+r2): pair base r=0:+, r=1:-, r=4:-, r=5:+
    const float4 mA = measA[qi], mB = measB[qi];
    const float aE_p  = mA.x + mA.w,  aE_m  = mA.x - mA.w;
    const float bEr_p = mA.y + mB.x,  bEr_m = mA.y - mB.x;
    const float bEi_p = mA.z + mB.y,  bEi_m = mA.z - mB.y;

    float p = 0.0f;
#pragma unroll
    for (int k = 0; k < 4; ++k) {
        const int lo = (k & 1) | ((k & 2) << 1);   // 0,1,4,5
        const int hi = lo | 2;
        const bool plus = (k == 0) || (k == 3);    // szz=+ for r=0,5
        const float aE  = plus ? aE_p  : aE_m;
        const float bEr = plus ? bEr_p : bEr_m;
        const float bEi = plus ? bEi_p : bEi_m;
        const float nn = (sr[lo]*sr[lo] + si[lo]*si[lo])
                       - (sr[hi]*sr[hi] + si[hi]*si[hi]);
        const float u  = sr[lo]*sr[hi] + si[lo]*si[hi];
        const float v  = sr[lo]*si[hi] - si[lo]*sr[hi];
        p += aE * nn + 2.0f * (bEr * u - bEi * v);
    }

    // reduce over the 16-lane group
    p += __shfl_xor(p, 1, 64);
    p += __shfl_xor(p, 2, 64);
    p += __shfl_xor(p, 4, 64);
    p += __shfl_xor(p, 8, 64);
    if ((lane & 15) == 0) zsh[sid][qi] = p;
    __syncthreads();

    // ---- FC epilogue, both samples in parallel ----
    const int sid2 = tid >> 8;
    const int t6   = tid & 255;
    if (t6 < NA) {
        float acc = fb[t6];
#pragma unroll
        for (int i = 0; i < NQ; ++i)
            acc += zsh[sid2][i] * fw[t6 * NQ + i];
        out[(2 * blk + sid2) * NA + t6] = acc;
    }
}

extern "C" void kernel_launch(void* const* d_in, const int* in_sizes, int n_in,
                              void* d_out, int out_size, void* d_ws, size_t ws_size,
                              hipStream_t stream) {
    const float* x    = (const float*)d_in[0];   // [512,16]
    const float* wts  = (const float*)d_in[1];   // [4,16,3]
    const float* fc_w = (const float*)d_in[2];   // [6,16]
    const float* fc_b = (const float*)d_in[3];   // [6]
    float* out = (float*)d_out;                  // [512,6]

    qdqn_kernel<<<BATCH / 2, 512, 0, stream>>>(x, wts, fc_w, fc_b, out);
}